// Round 9
// baseline (130.537 us; speedup 1.0000x reference)
//
#include <hip/hip_runtime.h>

#define GQ    8192                 // bs(32) * Gn(256)
#define WPB   4                    // waves per block (independent)
#define GPW   4                    // groups per wave, consecutive (share 128B lines)
#define NBLK  (GQ / (WPB * GPW))   // 512 blocks -> 2048 persistent waves

// ---- DPP cross-lane adds on the VALU pipe ----------------------------------
template <int CTRL>
__device__ __forceinline__ float dpp_add(float x) {
    // x + dpp_move(x); OOB source lanes contribute 0 (old=0, bound_ctrl=true).
    int t = __builtin_amdgcn_update_dpp(0, __float_as_int(x), CTRL, 0xf, 0xf, true);
    return x + __int_as_float(t);
}
__device__ __forceinline__ float wave_sum64(float x) {
    x = dpp_add<0x111>(x);   // row_shr:1
    x = dpp_add<0x112>(x);   // row_shr:2
    x = dpp_add<0x114>(x);   // row_shr:4
    x = dpp_add<0x118>(x);   // row_shr:8  -> lane15 of each row16 = row sum
    x = dpp_add<0x142>(x);   // row_bcast:15
    x = dpp_add<0x143>(x);   // row_bcast:31 -> lane 63 = full sum
    return x;
}
__device__ __forceinline__ float row_sum16(float x) {
    x = dpp_add<0x111>(x);
    x = dpp_add<0x112>(x);
    x = dpp_add<0x114>(x);
    x = dpp_add<0x118>(x);   // lane 15 = sum of lanes 0..15
    return x;
}
__device__ __forceinline__ float rdlane_f(float x, int lane) {
    return __int_as_float(__builtin_amdgcn_readlane(__float_as_int(x), lane));
}
#define COMP(v4, k) ((k)==0?(v4).x:((k)==1?(v4).y:((k)==2?(v4).z:(v4).w)))

// Persistent wave: 4 consecutive groups, rolling prefetch (next group's loads
// issued before current group's compute). Lane l owns channels (l, l+64).
// Cross-lane math on VALU (DPP/readlane/ballot); LDS only for the 44-float
// wave-private SIMM exchange (per-wave DS ordering makes fences unnecessary).
__global__ __launch_bounds__(64 * WPB, 2) void group_loss_kernel(
    const int*   __restrict__ labs,   // [G*16]
    const float* __restrict__ feats,  // [32,128,256,16]
    const int*   __restrict__ idxs,   // [G*16]
    const float* __restrict__ ctx,    // [128]
    float2* __restrict__ ws)          // [G] {gl*gv, gv}
{
    __shared__ float SH[WPB * 48];

    const int l  = threadIdx.x & 63;
    const int wu = threadIdx.x >> 6;
    float* SIMM = SH + wu * 48;

    const int blk = blockIdx.x;
    // XCD blk&7 owns groups [x<<10,(x+1)<<10); wave covers 4 consecutive groups
    const int gbase = ((blk & 7) << 10) | ((blk >> 3) << 4) | (wu << 2);
    const int b  = gbase >> 8;               // 4-chunk never crosses a b boundary
    const int gn = gbase & 255;
    const long fb0 = (long)b * (128 * 256 * 16) + (long)gn * 16;
    const float* gp = feats + fb0 + (long)l * 4096;   // lane channel l; +64*4096 for l+64

    const float cx0 = ctx[l], cx1 = ctx[l + 64];

    // double-buffered prefetch: buf[.][0..3]=chan l samples, [4..7]=chan l+64
    float4 buf[2][8];
    int blab[2] = {-2, -2}, bidx[2] = {-1, -1};
    #pragma unroll
    for (int q = 0; q < 4; ++q) {
        buf[0][q]     = *(const float4*)(gp + q * 4);
        buf[0][4 + q] = *(const float4*)(gp + 64 * 4096 + q * 4);
    }
    if (l < 16) { bidx[0] = idxs[gbase * 16 + l]; blab[0] = labs[gbase * 16 + l]; }

    #pragma unroll
    for (int t = 0; t < GPW; ++t) {
        const int cur = t & 1, nxt = cur ^ 1;

        // ---- issue next group's loads before current compute ----------------
        if (t + 1 < GPW) {
            const float* gq = gp + 16 * (t + 1);
            #pragma unroll
            for (int q = 0; q < 4; ++q) {
                buf[nxt][q]     = *(const float4*)(gq + q * 4);
                buf[nxt][4 + q] = *(const float4*)(gq + 64 * 4096 + q * 4);
            }
            if (l < 16) {
                bidx[nxt] = idxs[(gbase + t + 1) * 16 + l];
                blab[nxt] = labs[(gbase + t + 1) * 16 + l];
            }
        }

        const int g = gbase + t;
        const int myidx = (l < 16) ? bidx[cur] : -1;
        const int mylab = (l < 16) ? blab[cur] : -2;

        // ---- dup-check via readlane + ballot + mask algebra -----------------
        unsigned long long dupm = 0ULL;
        #pragma unroll
        for (int j = 0; j < 15; ++j) {
            const int sj = __builtin_amdgcn_readlane(myidx, j);
            const unsigned long long eq = __ballot(myidx == sj);
            dupm |= (eq & ~((2ULL << j) - 1ULL));
        }
        const int u = __popcll(~dupm & 0xFFFFULL);   // distinct seed count

        const bool valid = l < u;                    // u<=16
        const int bid = valid ? (mylab + 1) : 255;   // bucket 0=bg(-1), 1..8=fg

        int cnt[9];
        #pragma unroll
        for (int r = 0; r < 9; ++r) cnt[r] = __popcll(__ballot(bid == r));
        const bool has_bg = cnt[0] > 0;
        int fg_count = 0, pm = 0;
        #pragma unroll
        for (int r = 1; r < 9; ++r)
            if (cnt[r] > 0) { ++fg_count; pm |= 1 << r; }

        // ---- bucket sums: 16 uniform dispatches (readlane -> scalar switch) -
        float m0[9] = {0,0,0,0,0,0,0,0,0};
        float m1[9] = {0,0,0,0,0,0,0,0,0};
        #pragma unroll
        for (int s = 0; s < 16; ++s) {
            if (s < u) {
                const int bs = __builtin_amdgcn_readlane(bid, s);
                const float fas = COMP(buf[cur][s >> 2], s & 3);
                const float fbs = COMP(buf[cur][4 + (s >> 2)], s & 3);
                switch (bs) {
                    case 0: m0[0] += fas; m1[0] += fbs; break;
                    case 1: m0[1] += fas; m1[1] += fbs; break;
                    case 2: m0[2] += fas; m1[2] += fbs; break;
                    case 3: m0[3] += fas; m1[3] += fbs; break;
                    case 4: m0[4] += fas; m1[4] += fbs; break;
                    case 5: m0[5] += fas; m1[5] += fbs; break;
                    case 6: m0[6] += fas; m1[6] += fbs; break;
                    case 7: m0[7] += fas; m1[7] += fbs; break;
                    case 8: m0[8] += fas; m1[8] += fbs; break;
                }
            }
        }
        #pragma unroll
        for (int r = 0; r < 9; ++r) {
            const float invc = 1.0f / (float)(cnt[r] > 0 ? cnt[r] : 1);
            m0[r] *= invc; m1[r] *= invc;
        }
        if (!has_bg) { m0[0] = cx0; m1[0] = cx1; }   // row 0 = context_compen

        // ---- 44 pair dots via DPP wave reductions (pure VALU) ---------------
        float mine = 0.0f;
        {
            int p = 0;
            #pragma unroll
            for (int i = 1; i <= 8; ++i) {
                #pragma unroll
                for (int j = 0; j <= i; ++j) {
                    float x = m0[i] * m0[j] + m1[i] * m1[j];
                    x = wave_sum64(x);
                    const float sv = rdlane_f(x, 63);
                    mine = (l == p) ? sv : mine;
                    ++p;
                }
            }
        }
        mine *= 5.0f;                                // 1/T

        // ---- exchange 44 sims via wave-private LDS (in-order per wave) ------
        if (l < 44) SIMM[l] = mine;

        // ---- masked logsumexp per present fg row (lane r = row r) -----------
        float li_val = 0.0f;
        if (l >= 1 && l < 9 && ((pm >> l) & 1)) {
            const int r = l;
            float srow[9];
            #pragma unroll
            for (int j = 0; j < 9; ++j) {
                const int ii = (r > j) ? r : j;
                const int jj = (r > j) ? j : r;
                srow[j] = SIMM[ii * (ii + 1) / 2 - 1 + jj];
            }
            float vmax = srow[0];                    // col 0 (bg/ctx) always valid
            #pragma unroll
            for (int j = 1; j < 9; ++j)
                if ((pm >> j) & 1) vmax = fmaxf(vmax, srow[j]);
            float se = __expf(srow[0] - vmax);
            #pragma unroll
            for (int j = 1; j < 9; ++j)
                if ((pm >> j) & 1) se += __expf(srow[j] - vmax);
            li_val = vmax + __logf(se) - srow[r];
        }

        // ---- sum li over lanes 1..8; lane 0 stores --------------------------
        const float ssum = row_sum16(li_val);        // lane 15 = sum lanes 0..15
        const float tot  = rdlane_f(ssum, 15);
        if (l == 0) {
            float2 r;
            r.x = tot / (float)(fg_count > 0 ? fg_count : 1);  // gl*gv
            r.y = (fg_count > 0) ? 1.0f : 0.0f;                // gv
            ws[g] = r;
        }
    }
}

// Deterministic 8192 -> 1 reduction (float4 loads)
__global__ __launch_bounds__(1024) void reduce_kernel(
    const float4* __restrict__ ws4, float* __restrict__ out)
{
    __shared__ float sa[1024], sb[1024];
    const int t = threadIdx.x;
    float a = 0.0f, b2 = 0.0f;
    for (int i = t; i < GQ / 2; i += 1024) {     // 4096 float4 = 8192 float2
        float4 v = ws4[i];
        a += v.x + v.z; b2 += v.y + v.w;
    }
    sa[t] = a; sb[t] = b2;
    __syncthreads();
    for (int off = 512; off > 0; off >>= 1) {
        if (t < off) { sa[t] += sa[t + off]; sb[t] += sb[t + off]; }
        __syncthreads();
    }
    if (t == 0) out[0] = 0.1f * (sa[0] / sb[0]);
}

extern "C" void kernel_launch(void* const* d_in, const int* in_sizes, int n_in,
                              void* d_out, int out_size, void* d_ws, size_t ws_size,
                              hipStream_t stream) {
    const int*   labs  = (const int*)d_in[0];    // proposal_instance_mask
    const float* feats = (const float*)d_in[1];  // grouped_features
    const int*   idxs  = (const int*)d_in[2];    // grouped_indices
    const float* ctx   = (const float*)d_in[3];  // context_compen
    float* out = (float*)d_out;
    float2* ws = (float2*)d_ws;

    group_loss_kernel<<<NBLK, 64 * WPB, 0, stream>>>(labs, feats, idxs, ctx, ws);
    reduce_kernel<<<1, 1024, 0, stream>>>((const float4*)ws, out);
}